// Round 2
// baseline (157.752 us; speedup 1.0000x reference)
//
#include <hip/hip_runtime.h>
#include <math.h>

#define N_NODES 50000
#define N_EDGES 800000
#define IN_DIM 128
#define N_HEADS 4
#define OUT_DIM 32
#define PROJ_DIM 128   // N_HEADS * OUT_DIM
#define WSTR 144       // Wt LDS row stride in shorts (288 B, 16B-aligned)

#define NBIN 196       // ceil(50000/256): bin = src >> 8
#define BINCAP 5000    // edges per bin region (mean 4096, sigma ~64 -> 14 sigma)
#define MAXDEG 64      // gather clamp (max expected deg ~38 for Poisson(16))

#define PROJ_BLKS 391                    // ceil(50000/128), 128 rows/block
#define PART_BLKS 391                    // 2048 edges per block
#define TOTAL_BLKS (PROJ_BLKS + PART_BLKS)

typedef short bf16x8 __attribute__((ext_vector_type(8)));
typedef float f32x4  __attribute__((ext_vector_type(4)));
typedef _Float16 h2  __attribute__((ext_vector_type(2)));

// fp32 -> bf16 bits with round-to-nearest-even
__device__ __forceinline__ ushort f32_to_bf16(float f) {
    unsigned u = __float_as_uint(f);
    unsigned r = u + 0x7fffu + ((u >> 16) & 1u);
    return (ushort)(r >> 16);
}

__device__ __forceinline__ float bf16_to_f32(ushort v) {
    return __uint_as_float((unsigned)v << 16);
}

__device__ __forceinline__ bf16x8 cvt8(float4 a, float4 b) {
    bf16x8 r;
    r[0] = (short)f32_to_bf16(a.x); r[1] = (short)f32_to_bf16(a.y);
    r[2] = (short)f32_to_bf16(a.z); r[3] = (short)f32_to_bf16(a.w);
    r[4] = (short)f32_to_bf16(b.x); r[5] = (short)f32_to_bf16(b.y);
    r[6] = (short)f32_to_bf16(b.z); r[7] = (short)f32_to_bf16(b.w);
    return r;
}

// ---------------------------------------------------------------------------
// K1: BLOCK-SPECIALIZED combo (unchanged).
//  blocks [0,PROJ_BLKS): proj = X @ W via bf16 MFMA 16x16x32.
//  blocks [PROJ_BLKS,..): edge partition into 196 coarse bins (src>>8):
//    LDS histogram + 196 global returning atomics per block + packed stores.
// ---------------------------------------------------------------------------
__global__ __launch_bounds__(256) void combo_kernel(
    const float* __restrict__ X, const float* __restrict__ W,
    const float* __restrict__ att, const int* __restrict__ ei,
    ushort* __restrict__ projT, float* __restrict__ s_src, float* __restrict__ s_tgt,
    int* __restrict__ bin_cursor, unsigned* __restrict__ slab)
{
    __shared__ ushort Wt[128 * WSTR];   // 36.9 KB (partition blocks alias it)

    const int tid = threadIdx.x;

    if (blockIdx.x >= PROJ_BLKS) {
        // ---------------- partition part: 2048 edges per block -----------
        int* cnt   = (int*)Wt;          // 196 ints (aliased onto Wt storage)
        int* gbase = cnt + 256;         // 196 ints

        for (int t = tid; t < NBIN; t += 256) cnt[t] = 0;
        __syncthreads();

        const int ebase = (blockIdx.x - PROJ_BLKS) * 2048;
        unsigned srcv[8], tgtv[8];
        int rank[8];
#pragma unroll
        for (int i = 0; i < 8; ++i) {
            int e = ebase + i * 256 + tid;
            bool ok = e < N_EDGES;
            srcv[i] = ok ? (unsigned)ei[e] : 0u;
            tgtv[i] = ok ? (unsigned)ei[N_EDGES + e] : 0u;
            rank[i] = ok ? atomicAdd(&cnt[srcv[i] >> 8], 1) : -1;
        }
        __syncthreads();

        for (int t = tid; t < NBIN; t += 256)
            gbase[t] = atomicAdd(&bin_cursor[t], cnt[t]);   // 196/block global
        __syncthreads();

#pragma unroll
        for (int i = 0; i < 8; ++i) {
            if (rank[i] >= 0) {
                int bin = srcv[i] >> 8;
                int p = gbase[bin] + rank[i];
                if (p < BINCAP)
                    slab[bin * BINCAP + p] = (tgtv[i] << 16) | (srcv[i] & 255u);
            }
        }
        return;
    }

    // ------------------------- proj part ---------------------------------
    for (int idx = tid; idx < 64 * 128; idx += 256) {
        int kp = idx >> 7;
        int c  = idx & 127;
        float w0 = W[(2 * kp) * PROJ_DIM + c];
        float w1 = W[(2 * kp + 1) * PROJ_DIM + c];
        unsigned pr = (unsigned)f32_to_bf16(w0) | ((unsigned)f32_to_bf16(w1) << 16);
        *(unsigned*)&Wt[c * WSTR + 2 * kp] = pr;
    }
    __syncthreads();

    const int wv   = tid >> 6;
    const int lane = tid & 63;
    const int m = lane & 15;
    const int q = lane >> 4;
    const int rbase = blockIdx.x * 128;

    int arow0 = rbase + wv * 32 + m;
    int arow1 = arow0 + 16;
    arow0 = (arow0 < N_NODES) ? arow0 : N_NODES - 1;
    arow1 = (arow1 < N_NODES) ? arow1 : N_NODES - 1;
    const long long xb0 = (long long)arow0 * IN_DIM;
    const long long xb1 = (long long)arow1 * IN_DIM;

    f32x4 acc[2][8];
#pragma unroll
    for (int rt = 0; rt < 2; ++rt)
#pragma unroll
        for (int ct = 0; ct < 8; ++ct) acc[rt][ct] = (f32x4){0.f, 0.f, 0.f, 0.f};

#pragma unroll
    for (int ks = 0; ks < 4; ++ks) {
        const int k0 = ks * 32 + q * 8;
        float4 a0lo = *(const float4*)&X[xb0 + k0];
        float4 a0hi = *(const float4*)&X[xb0 + k0 + 4];
        float4 a1lo = *(const float4*)&X[xb1 + k0];
        float4 a1hi = *(const float4*)&X[xb1 + k0 + 4];
        bf16x8 afrag0 = cvt8(a0lo, a0hi);
        bf16x8 afrag1 = cvt8(a1lo, a1hi);
#pragma unroll
        for (int ct = 0; ct < 8; ++ct) {
            bf16x8 bfrag = *(const bf16x8*)&Wt[(ct * 16 + m) * WSTR + k0];
            acc[0][ct] = __builtin_amdgcn_mfma_f32_16x16x32_bf16(afrag0, bfrag, acc[0][ct], 0, 0, 0);
            acc[1][ct] = __builtin_amdgcn_mfma_f32_16x16x32_bf16(afrag1, bfrag, acc[1][ct], 0, 0, 0);
        }
    }

    const float as_lo = att[m],      as_hi = att[m + 16];
    const float at_lo = att[32 + m], at_hi = att[48 + m];

#pragma unroll
    for (int rt = 0; rt < 2; ++rt) {
        const int rowb = rbase + wv * 32 + rt * 16 + q * 4;
#pragma unroll
        for (int r = 0; r < 4; ++r) {
            const int row = rowb + r;
            float cl[4], ch[4];
#pragma unroll
            for (int h = 0; h < 4; ++h) {
                cl[h] = acc[rt][2 * h][r];
                ch[h] = acc[rt][2 * h + 1][r];
            }
            if (row < N_NODES) {
                ushort4 plo, phi;
                plo.x = f32_to_bf16(cl[0]); plo.y = f32_to_bf16(cl[1]);
                plo.z = f32_to_bf16(cl[2]); plo.w = f32_to_bf16(cl[3]);
                phi.x = f32_to_bf16(ch[0]); phi.y = f32_to_bf16(ch[1]);
                phi.z = f32_to_bf16(ch[2]); phi.w = f32_to_bf16(ch[3]);
                *(ushort4*)&projT[(long long)row * PROJ_DIM + m * 4] = plo;
                *(ushort4*)&projT[(long long)row * PROJ_DIM + (m + 16) * 4] = phi;
            }
            float ps[4], pt[4];
#pragma unroll
            for (int h = 0; h < 4; ++h) {
                ps[h] = cl[h] * as_lo + ch[h] * as_hi;
                pt[h] = cl[h] * at_lo + ch[h] * at_hi;
            }
#pragma unroll
            for (int off = 8; off > 0; off >>= 1) {
#pragma unroll
                for (int h = 0; h < 4; ++h) {
                    ps[h] += __shfl_down(ps[h], off, 16);
                    pt[h] += __shfl_down(pt[h], off, 16);
                }
            }
            if (m == 0 && row < N_NODES) {
                *(float4*)&s_src[row * N_HEADS] = make_float4(ps[0], ps[1], ps[2], ps[3]);
                *(float4*)&s_tgt[row * N_HEADS] = make_float4(pt[0], pt[1], pt[2], pt[3]);
            }
        }
    }
}

// ---------------------------------------------------------------------------
// K2: binsort (unchanged from R1). One block per bin; LDS-only atomics,
// wave-level __shfl_up scan (2 barriers), LDS scatter, coalesced CSR dump.
// ---------------------------------------------------------------------------
__global__ __launch_bounds__(256) void binsort_kernel(
    const unsigned* __restrict__ slab, const int* __restrict__ bin_cursor,
    ushort* __restrict__ csr, int* __restrict__ offs, int* __restrict__ deg)
{
    __shared__ int cnt2[256];
    __shared__ int ex[256];
    __shared__ int wsum[4];
    __shared__ ushort stgt[BINCAP];    // 10 KB

    const int b = blockIdx.x;
    const int t = threadIdx.x;
    const int lane = t & 63;
    const int wid  = t >> 6;
    int n_e = bin_cursor[b];
    n_e = (n_e < BINCAP) ? n_e : BINCAP;

    cnt2[t] = 0;
    __syncthreads();

    unsigned pk[20];                   // (tgt<<16)|(rank<<8)|node8
    int npk = 0;
    for (int i = t; i < n_e; i += 256) {
        unsigned v = slab[b * BINCAP + i];
        int node8 = v & 255u;
        int r = atomicAdd(&cnt2[node8], 1);
        r = (r < 255) ? r : 255;
        pk[npk++] = (v & 0xFFFF0000u) | ((unsigned)r << 8) | (unsigned)node8;
    }
    __syncthreads();

    // wave-level inclusive scan over 64 lanes (shuffles unconditional)
    const int v = cnt2[t];
    int x = v;
#pragma unroll
    for (int off = 1; off < 64; off <<= 1) {
        int y = __shfl_up(x, off);
        x += (lane >= off) ? y : 0;
    }
    if (lane == 63) wsum[wid] = x;
    __syncthreads();
    int add = 0;
#pragma unroll
    for (int w = 0; w < 4; ++w) add += (w < wid) ? wsum[w] : 0;
    ex[t] = x + add - v;               // exclusive prefix
    __syncthreads();

    for (int j = 0; j < npk; ++j) {
        unsigned pv = pk[j];
        int lpos = ex[pv & 255u] + (int)((pv >> 8) & 255u);
        if (lpos < BINCAP) stgt[lpos] = (ushort)(pv >> 16);
    }
    __syncthreads();

    for (int i = t; i < n_e; i += 256) csr[b * BINCAP + i] = stgt[i];
    int node = b * 256 + t;
    if (node < N_NODES) {
        offs[node] = b * BINCAP + ex[t];
        deg[node]  = cnt2[t];
    }
}

// ---------------------------------------------------------------------------
// K3: gather v4 — barrier-free, LDS-free. One WAVE per node.
//   CHANGE vs v3: dead-slot projT loads are exec-masked away. Slot liveness
//   (sl = j + 2u + half < n) is HALF-WAVE-UNIFORM, so `if (sl < n) load`
//   costs only a uniform branch per half and issues ZERO memory transactions
//   for dead slots — removing the 43% gather-traffic overshoot v3 introduced
//   (E[16*ceil(n/16)] = 22.9 vs E[n] = 16 for Poisson(16)).
//   Shuffles stay unconditional (full EXEC — ds_bpermute from an inactive
//   source lane is undefined). p[u] is zero-initialized for dead slots so
//   0-alpha FMAs can't meet garbage/NaN bits. Three separate unrolled loops
//   (shuffles / loads / FMAs) keep 8 loads outstanding per lane.
// ---------------------------------------------------------------------------
__global__ __launch_bounds__(256) void gather_kernel(
    const int* __restrict__ deg, const int* __restrict__ offs,
    const ushort* __restrict__ csr,
    const float* __restrict__ s_src, const float* __restrict__ s_tgt,
    const ushort* __restrict__ projT, float* __restrict__ out)
{
    const int wv   = threadIdx.x >> 6;
    const int lane = threadIdx.x & 63;
    const int node = blockIdx.x * 4 + wv;  // N_NODES = 12500*4

    int n = deg[node];
    n = (n < MAXDEG) ? n : MAXDEG;
    const int o = offs[node];

    int mytgt = 0, myA01 = 0, myA23 = 0;
    if (lane < n) {
        int tgt = csr[o + lane];                            // coalesced ushort
        float4 ss = *(const float4*)&s_src[node * N_HEADS]; // wave-uniform
        float4 st = *(const float4*)&s_tgt[tgt * N_HEADS];  // parallel gather

        float sc[4] = { ss.x + st.x, ss.y + st.y, ss.z + st.z, ss.w + st.w };
        float mx = -1e30f;
#pragma unroll
        for (int h = 0; h < 4; ++h) {
            sc[h] = (sc[h] > 0.0f) ? sc[h] : 0.01f * sc[h];  // leaky_relu
            mx = fmaxf(mx, sc[h]);
        }
        float sum = 0.0f;
#pragma unroll
        for (int h = 0; h < 4; ++h) {
            sc[h] = __expf(sc[h] - mx);
            sum += sc[h];
        }
        float inv = 0.25f / sum;     // softmax normalize * head-mean

        h2 a01, a23;
        a01.x = (_Float16)(sc[0] * inv);
        a01.y = (_Float16)(sc[1] * inv);
        a23.x = (_Float16)(sc[2] * inv);
        a23.y = (_Float16)(sc[3] * inv);
        mytgt = tgt;
        myA01 = __builtin_bit_cast(int, a01);
        myA23 = __builtin_bit_cast(int, a23);
    }
    // no barrier: producers and consumers are the same wave

    const int d    = lane & 31;
    const int half = lane >> 5;

    float acc0 = 0.0f, acc1 = 0.0f, acc2 = 0.0f, acc3 = 0.0f;

    // Unified predicated pass: 16 edge slots per iteration (8 per half),
    // up to 8 outstanding projT gathers per lane; dead slots issue no loads.
    for (int j = 0; j < n; j += 16) {
        int tg[8], ea[8], eb[8];
#pragma unroll
        for (int u = 0; u < 8; ++u) {
            int sl = j + 2 * u + half;
            bool ok = sl < n;
            int slc = ok ? sl : 0;
            int tgv = __shfl(mytgt, slc);   // unconditional, full EXEC
            int eav = __shfl(myA01, slc);
            int ebv = __shfl(myA23, slc);
            tg[u] = tgv;
            ea[u] = ok ? eav : 0;
            eb[u] = ok ? ebv : 0;
        }
        ushort4 p[8];
#pragma unroll
        for (int u = 0; u < 8; ++u) {
            ushort4 pv; pv.x = 0; pv.y = 0; pv.z = 0; pv.w = 0;
            if (j + 2 * u + half < n)       // half-uniform: dead half -> no load
                pv = *(const ushort4*)&projT[(long long)tg[u] * PROJ_DIM + d * 4];
            p[u] = pv;
        }
#pragma unroll
        for (int u = 0; u < 8; ++u) {
            h2 a = __builtin_bit_cast(h2, ea[u]);
            h2 b = __builtin_bit_cast(h2, eb[u]);
            float* accp = (u & 1) ? ((u & 2) ? &acc3 : &acc1)
                                  : ((u & 2) ? &acc2 : &acc0);
            float tt = *accp;
            tt = fmaf((float)a.x, bf16_to_f32(p[u].x), tt);
            tt = fmaf((float)a.y, bf16_to_f32(p[u].y), tt);
            tt = fmaf((float)b.x, bf16_to_f32(p[u].z), tt);
            tt = fmaf((float)b.y, bf16_to_f32(p[u].w), tt);
            *accp = tt;
        }
    }

    float acc = (acc0 + acc1) + (acc2 + acc3);
    acc += __shfl_down(acc, 32);      // combine the two halves (width 64)
    if (lane < 32) out[node * OUT_DIM + d] = acc;
}

extern "C" void kernel_launch(void* const* d_in, const int* in_sizes, int n_in,
                              void* d_out, int out_size, void* d_ws, size_t ws_size,
                              hipStream_t stream) {
    const float* X   = (const float*)d_in[0];
    const int*   ei  = (const int*)d_in[1];
    const float* W   = (const float*)d_in[2];
    const float* att = (const float*)d_in[3];
    float* out = (float*)d_out;

    // workspace layout, total ~20.8 MB
    char* p = (char*)d_ws;
    ushort* projT   = (ushort*)p;   p += (size_t)N_NODES * PROJ_DIM * 2;  // 12.8 MB
    float* s_src    = (float*)p;    p += (size_t)N_NODES * N_HEADS * 4;   // 0.8 MB
    float* s_tgt    = (float*)p;    p += (size_t)N_NODES * N_HEADS * 4;   // 0.8 MB
    unsigned* slab  = (unsigned*)p; p += (size_t)NBIN * BINCAP * 4;       // 3.92 MB
    ushort* csr     = (ushort*)p;   p += (size_t)NBIN * BINCAP * 2;       // 1.96 MB
    int* offs       = (int*)p;      p += (size_t)N_NODES * 4;             // 0.2 MB
    int* deg        = (int*)p;      p += (size_t)N_NODES * 4;             // 0.2 MB
    int* bin_cursor = (int*)p;      p += 256 * 4;

    (void)hipMemsetAsync(bin_cursor, 0, 256 * sizeof(int), stream);

    combo_kernel<<<TOTAL_BLKS, 256, 0, stream>>>(
        X, W, att, ei, projT, s_src, s_tgt, bin_cursor, slab);

    binsort_kernel<<<NBIN, 256, 0, stream>>>(slab, bin_cursor, csr, offs, deg);

    gather_kernel<<<N_NODES / 4, 256, 0, stream>>>(
        deg, offs, csr, s_src, s_tgt, projT, out);
}

// Round 3
// 151.212 us; speedup vs baseline: 1.0433x; 1.0433x over previous
//
#include <hip/hip_runtime.h>
#include <math.h>

#define N_NODES 50000
#define N_EDGES 800000
#define IN_DIM 128
#define N_HEADS 4
#define OUT_DIM 32
#define PROJ_DIM 128   // N_HEADS * OUT_DIM
#define WSTR 144       // Wt LDS row stride in shorts (288 B, 16B-aligned)

#define MAXDEG 64      // per-node CSR capacity (Poisson(16): P(deg>64) ~ 1e-20)

#define PROJ_BLKS 391                    // ceil(50000/128), 128 rows/block
#define PART_BLKS 391                    // 2048 edges per block
#define TOTAL_BLKS (PROJ_BLKS + PART_BLKS)

typedef short bf16x8 __attribute__((ext_vector_type(8)));
typedef float f32x4  __attribute__((ext_vector_type(4)));
typedef _Float16 h2  __attribute__((ext_vector_type(2)));

// fp32 -> bf16 bits with round-to-nearest-even
__device__ __forceinline__ ushort f32_to_bf16(float f) {
    unsigned u = __float_as_uint(f);
    unsigned r = u + 0x7fffu + ((u >> 16) & 1u);
    return (ushort)(r >> 16);
}

__device__ __forceinline__ float bf16_to_f32(ushort v) {
    return __uint_as_float((unsigned)v << 16);
}

__device__ __forceinline__ bf16x8 cvt8(float4 a, float4 b) {
    bf16x8 r;
    r[0] = (short)f32_to_bf16(a.x); r[1] = (short)f32_to_bf16(a.y);
    r[2] = (short)f32_to_bf16(a.z); r[3] = (short)f32_to_bf16(a.w);
    r[4] = (short)f32_to_bf16(b.x); r[5] = (short)f32_to_bf16(b.y);
    r[6] = (short)f32_to_bf16(b.z); r[7] = (short)f32_to_bf16(b.w);
    return r;
}

// ---------------------------------------------------------------------------
// K1: BLOCK-SPECIALIZED combo.
//  blocks [0,PROJ_BLKS): proj = X @ W via bf16 MFMA 16x16x32 (unchanged).
//  blocks [PROJ_BLKS,..): DIRECT per-node CSR scatter (replaces the whole
//    bin+binsort pipeline): rank = atomicAdd(&deg[src],1) (device-scope,
//    ~16 hits per address -> negligible contention), then a 2 B store of
//    tgt into the node's fixed-capacity row. No LDS, no barriers, no slab,
//    and the binsort kernel is DELETED.
// ---------------------------------------------------------------------------
__global__ __launch_bounds__(256) void combo_kernel(
    const float* __restrict__ X, const float* __restrict__ W,
    const float* __restrict__ att, const int* __restrict__ ei,
    ushort* __restrict__ projT, float* __restrict__ s_src, float* __restrict__ s_tgt,
    int* __restrict__ deg, ushort* __restrict__ csr)
{
    __shared__ ushort Wt[128 * WSTR];   // 36.9 KB (partition blocks don't touch it)

    const int tid = threadIdx.x;

    if (blockIdx.x >= PROJ_BLKS) {
        // ------------- partition part: 2048 edges per block --------------
        const int ebase = (blockIdx.x - PROJ_BLKS) * 2048;
#pragma unroll
        for (int i = 0; i < 8; ++i) {
            int e = ebase + i * 256 + tid;
            if (e < N_EDGES) {
                unsigned s = (unsigned)ei[e];
                unsigned t = (unsigned)ei[N_EDGES + e];
                int r = atomicAdd(&deg[s], 1);
                if (r < MAXDEG)
                    csr[(long long)s * MAXDEG + r] = (ushort)t;
            }
        }
        return;
    }

    // ------------------------- proj part ---------------------------------
    for (int idx = tid; idx < 64 * 128; idx += 256) {
        int kp = idx >> 7;
        int c  = idx & 127;
        float w0 = W[(2 * kp) * PROJ_DIM + c];
        float w1 = W[(2 * kp + 1) * PROJ_DIM + c];
        unsigned pr = (unsigned)f32_to_bf16(w0) | ((unsigned)f32_to_bf16(w1) << 16);
        *(unsigned*)&Wt[c * WSTR + 2 * kp] = pr;
    }
    __syncthreads();

    const int wv   = tid >> 6;
    const int lane = tid & 63;
    const int m = lane & 15;
    const int q = lane >> 4;
    const int rbase = blockIdx.x * 128;

    int arow0 = rbase + wv * 32 + m;
    int arow1 = arow0 + 16;
    arow0 = (arow0 < N_NODES) ? arow0 : N_NODES - 1;
    arow1 = (arow1 < N_NODES) ? arow1 : N_NODES - 1;
    const long long xb0 = (long long)arow0 * IN_DIM;
    const long long xb1 = (long long)arow1 * IN_DIM;

    f32x4 acc[2][8];
#pragma unroll
    for (int rt = 0; rt < 2; ++rt)
#pragma unroll
        for (int ct = 0; ct < 8; ++ct) acc[rt][ct] = (f32x4){0.f, 0.f, 0.f, 0.f};

#pragma unroll
    for (int ks = 0; ks < 4; ++ks) {
        const int k0 = ks * 32 + q * 8;
        float4 a0lo = *(const float4*)&X[xb0 + k0];
        float4 a0hi = *(const float4*)&X[xb0 + k0 + 4];
        float4 a1lo = *(const float4*)&X[xb1 + k0];
        float4 a1hi = *(const float4*)&X[xb1 + k0 + 4];
        bf16x8 afrag0 = cvt8(a0lo, a0hi);
        bf16x8 afrag1 = cvt8(a1lo, a1hi);
#pragma unroll
        for (int ct = 0; ct < 8; ++ct) {
            bf16x8 bfrag = *(const bf16x8*)&Wt[(ct * 16 + m) * WSTR + k0];
            acc[0][ct] = __builtin_amdgcn_mfma_f32_16x16x32_bf16(afrag0, bfrag, acc[0][ct], 0, 0, 0);
            acc[1][ct] = __builtin_amdgcn_mfma_f32_16x16x32_bf16(afrag1, bfrag, acc[1][ct], 0, 0, 0);
        }
    }

    const float as_lo = att[m],      as_hi = att[m + 16];
    const float at_lo = att[32 + m], at_hi = att[48 + m];

#pragma unroll
    for (int rt = 0; rt < 2; ++rt) {
        const int rowb = rbase + wv * 32 + rt * 16 + q * 4;
#pragma unroll
        for (int r = 0; r < 4; ++r) {
            const int row = rowb + r;
            float cl[4], ch[4];
#pragma unroll
            for (int h = 0; h < 4; ++h) {
                cl[h] = acc[rt][2 * h][r];
                ch[h] = acc[rt][2 * h + 1][r];
            }
            if (row < N_NODES) {
                ushort4 plo, phi;
                plo.x = f32_to_bf16(cl[0]); plo.y = f32_to_bf16(cl[1]);
                plo.z = f32_to_bf16(cl[2]); plo.w = f32_to_bf16(cl[3]);
                phi.x = f32_to_bf16(ch[0]); phi.y = f32_to_bf16(ch[1]);
                phi.z = f32_to_bf16(ch[2]); phi.w = f32_to_bf16(ch[3]);
                *(ushort4*)&projT[(long long)row * PROJ_DIM + m * 4] = plo;
                *(ushort4*)&projT[(long long)row * PROJ_DIM + (m + 16) * 4] = phi;
            }
            float ps[4], pt[4];
#pragma unroll
            for (int h = 0; h < 4; ++h) {
                ps[h] = cl[h] * as_lo + ch[h] * as_hi;
                pt[h] = cl[h] * at_lo + ch[h] * at_hi;
            }
#pragma unroll
            for (int off = 8; off > 0; off >>= 1) {
#pragma unroll
                for (int h = 0; h < 4; ++h) {
                    ps[h] += __shfl_down(ps[h], off, 16);
                    pt[h] += __shfl_down(pt[h], off, 16);
                }
            }
            if (m == 0 && row < N_NODES) {
                *(float4*)&s_src[row * N_HEADS] = make_float4(ps[0], ps[1], ps[2], ps[3]);
                *(float4*)&s_tgt[row * N_HEADS] = make_float4(pt[0], pt[1], pt[2], pt[3]);
            }
        }
    }
}

// ---------------------------------------------------------------------------
// K3: gather — EXACT R1 structure (the fastest measured: 145.2 µs total).
//   One WAVE per node, barrier-free, LDS-free. Unified 16-slot pass with
//   UNCONDITIONAL loads (R2's exec-masked loads broke the 8-load clause and
//   regressed 12.5 µs; the "extra" tail loads are L2 hits — gather is
//   latency/VALU-bound at 23% HBM, so bytes are not the cost). csr is now
//   the fixed-stride per-node layout (node*MAXDEG), offs[] is gone.
// ---------------------------------------------------------------------------
__global__ __launch_bounds__(256) void gather_kernel(
    const int* __restrict__ deg, const ushort* __restrict__ csr,
    const float* __restrict__ s_src, const float* __restrict__ s_tgt,
    const ushort* __restrict__ projT, float* __restrict__ out)
{
    const int wv   = threadIdx.x >> 6;
    const int lane = threadIdx.x & 63;
    const int node = blockIdx.x * 4 + wv;  // N_NODES = 12500*4

    int n = deg[node];
    n = (n < MAXDEG) ? n : MAXDEG;
    const long long o = (long long)node * MAXDEG;

    int mytgt = 0, myA01 = 0, myA23 = 0;
    if (lane < n) {
        int tgt = csr[o + lane];                            // coalesced ushort
        float4 ss = *(const float4*)&s_src[node * N_HEADS]; // wave-uniform
        float4 st = *(const float4*)&s_tgt[tgt * N_HEADS];  // parallel gather

        float sc[4] = { ss.x + st.x, ss.y + st.y, ss.z + st.z, ss.w + st.w };
        float mx = -1e30f;
#pragma unroll
        for (int h = 0; h < 4; ++h) {
            sc[h] = (sc[h] > 0.0f) ? sc[h] : 0.01f * sc[h];  // leaky_relu
            mx = fmaxf(mx, sc[h]);
        }
        float sum = 0.0f;
#pragma unroll
        for (int h = 0; h < 4; ++h) {
            sc[h] = __expf(sc[h] - mx);
            sum += sc[h];
        }
        float inv = 0.25f / sum;     // softmax normalize * head-mean

        h2 a01, a23;
        a01.x = (_Float16)(sc[0] * inv);
        a01.y = (_Float16)(sc[1] * inv);
        a23.x = (_Float16)(sc[2] * inv);
        a23.y = (_Float16)(sc[3] * inv);
        mytgt = tgt;
        myA01 = __builtin_bit_cast(int, a01);
        myA23 = __builtin_bit_cast(int, a23);
    }
    // no barrier: producers and consumers are the same wave

    const int d    = lane & 31;
    const int half = lane >> 5;

    float acc0 = 0.0f, acc1 = 0.0f, acc2 = 0.0f, acc3 = 0.0f;

    // Unified pass: 16 edge slots per iteration (8 per half), 8 outstanding
    // projT gathers per lane, tail handled by clamp+zero on the ALPHAS only.
    for (int j = 0; j < n; j += 16) {
        int tg[8], ea[8], eb[8];
#pragma unroll
        for (int u = 0; u < 8; ++u) {
            int sl = j + 2 * u + half;
            bool ok = sl < n;
            int slc = ok ? sl : 0;
            int tgv = __shfl(mytgt, slc);   // unconditional, full EXEC
            int eav = __shfl(myA01, slc);
            int ebv = __shfl(myA23, slc);
            tg[u] = tgv;
            ea[u] = ok ? eav : 0;
            eb[u] = ok ? ebv : 0;
        }
        ushort4 p[8];
#pragma unroll
        for (int u = 0; u < 8; ++u)
            p[u] = *(const ushort4*)&projT[(long long)tg[u] * PROJ_DIM + d * 4];
#pragma unroll
        for (int u = 0; u < 8; ++u) {
            h2 a = __builtin_bit_cast(h2, ea[u]);
            h2 b = __builtin_bit_cast(h2, eb[u]);
            float* accp = (u & 1) ? ((u & 2) ? &acc3 : &acc1)
                                  : ((u & 2) ? &acc2 : &acc0);
            float tt = *accp;
            tt = fmaf((float)a.x, bf16_to_f32(p[u].x), tt);
            tt = fmaf((float)a.y, bf16_to_f32(p[u].y), tt);
            tt = fmaf((float)b.x, bf16_to_f32(p[u].z), tt);
            tt = fmaf((float)b.y, bf16_to_f32(p[u].w), tt);
            *accp = tt;
        }
    }

    float acc = (acc0 + acc1) + (acc2 + acc3);
    acc += __shfl_down(acc, 32);      // combine the two halves (width 64)
    if (lane < 32) out[node * OUT_DIM + d] = acc;
}

extern "C" void kernel_launch(void* const* d_in, const int* in_sizes, int n_in,
                              void* d_out, int out_size, void* d_ws, size_t ws_size,
                              hipStream_t stream) {
    const float* X   = (const float*)d_in[0];
    const int*   ei  = (const int*)d_in[1];
    const float* W   = (const float*)d_in[2];
    const float* att = (const float*)d_in[3];
    float* out = (float*)d_out;

    // workspace layout, total ~21 MB
    char* p = (char*)d_ws;
    ushort* projT   = (ushort*)p;   p += (size_t)N_NODES * PROJ_DIM * 2;  // 12.8 MB
    float* s_src    = (float*)p;    p += (size_t)N_NODES * N_HEADS * 4;   // 0.8 MB
    float* s_tgt    = (float*)p;    p += (size_t)N_NODES * N_HEADS * 4;   // 0.8 MB
    ushort* csr     = (ushort*)p;   p += (size_t)N_NODES * MAXDEG * 2;    // 6.4 MB
    int* deg        = (int*)p;      p += (size_t)N_NODES * 4;             // 0.2 MB

    (void)hipMemsetAsync(deg, 0, (size_t)N_NODES * sizeof(int), stream);

    combo_kernel<<<TOTAL_BLKS, 256, 0, stream>>>(
        X, W, att, ei, projT, s_src, s_tgt, deg, csr);

    gather_kernel<<<N_NODES / 4, 256, 0, stream>>>(
        deg, csr, s_src, s_tgt, projT, out);
}

// Round 5
// 142.070 us; speedup vs baseline: 1.1104x; 1.0643x over previous
//
#include <hip/hip_runtime.h>
#include <math.h>

#define N_NODES 50000
#define N_EDGES 800000
#define IN_DIM 128
#define N_HEADS 4
#define OUT_DIM 32
#define PROJ_DIM 128   // N_HEADS * OUT_DIM
#define WSTR 144       // Wt LDS row stride in shorts (288 B, 16B-aligned)

#define NBIN 196       // ceil(50000/256): bin = src >> 8
#define BINCAP 5000    // edges per bin region (mean 4096, sigma ~64 -> 14 sigma)
#define MAXDEG 64      // gather clamp (max expected deg ~38 for Poisson(16))

#define PROJ_BLKS 391                    // ceil(50000/128), 128 rows/block
#define PART_BLKS 391                    // 2048 edges per block
#define FUSE_BLKS (NBIN + PROJ_BLKS)     // K2: binsort blocks first, then proj

typedef short bf16x8 __attribute__((ext_vector_type(8)));
typedef float f32x4  __attribute__((ext_vector_type(4)));
typedef _Float16 h2  __attribute__((ext_vector_type(2)));

// fp32 -> bf16 bits with round-to-nearest-even
__device__ __forceinline__ ushort f32_to_bf16(float f) {
    unsigned u = __float_as_uint(f);
    unsigned r = u + 0x7fffu + ((u >> 16) & 1u);
    return (ushort)(r >> 16);
}

__device__ __forceinline__ float bf16_to_f32(ushort v) {
    return __uint_as_float((unsigned)v << 16);
}

__device__ __forceinline__ bf16x8 cvt8(float4 a, float4 b) {
    bf16x8 r;
    r[0] = (short)f32_to_bf16(a.x); r[1] = (short)f32_to_bf16(a.y);
    r[2] = (short)f32_to_bf16(a.z); r[3] = (short)f32_to_bf16(a.w);
    r[4] = (short)f32_to_bf16(b.x); r[5] = (short)f32_to_bf16(b.y);
    r[6] = (short)f32_to_bf16(b.z); r[7] = (short)f32_to_bf16(b.w);
    return r;
}

// ---------------------------------------------------------------------------
// K1: partition only (R1's proven bin scheme, standalone). 2048 edges/block.
// LDS histogram over 196 coarse bins (src>>8), 196 returning global atomics
// per block, then PACKED slab stores (append runs per bin -> good locality,
// no cross-XCD line ping-pong, unlike R3's direct scatter).
// ---------------------------------------------------------------------------
__global__ __launch_bounds__(256) void partition_kernel(
    const int* __restrict__ ei, int* __restrict__ bin_cursor,
    unsigned* __restrict__ slab)
{
    __shared__ int cnt[256];
    __shared__ int gbase[256];

    const int tid = threadIdx.x;

    for (int t = tid; t < NBIN; t += 256) cnt[t] = 0;
    __syncthreads();

    const int ebase = blockIdx.x * 2048;
    unsigned srcv[8], tgtv[8];
    int rank[8];
#pragma unroll
    for (int i = 0; i < 8; ++i) {
        int e = ebase + i * 256 + tid;
        bool ok = e < N_EDGES;
        srcv[i] = ok ? (unsigned)ei[e] : 0u;
        tgtv[i] = ok ? (unsigned)ei[N_EDGES + e] : 0u;
        rank[i] = ok ? atomicAdd(&cnt[srcv[i] >> 8], 1) : -1;
    }
    __syncthreads();

    for (int t = tid; t < NBIN; t += 256)
        gbase[t] = atomicAdd(&bin_cursor[t], cnt[t]);   // 196/block global
    __syncthreads();

#pragma unroll
    for (int i = 0; i < 8; ++i) {
        if (rank[i] >= 0) {
            int bin = srcv[i] >> 8;
            int p = gbase[bin] + rank[i];
            if (p < BINCAP)
                slab[bin * BINCAP + p] = (tgtv[i] << 16) | (srcv[i] & 255u);
        }
    }
}

// ---------------------------------------------------------------------------
// K2: proj + binsort FUSED by block specialization.
//  blocks [0, NBIN): binsort one bin each (R1 binsort; LDS aliased onto Wt).
//  blocks [NBIN, FUSE_BLKS): proj = X @ W via bf16 MFMA 16x16x32 (R1 proj).
// Binsort depends only on K1's slab/cursors; proj depends only on X/W ->
// the two block populations run CONCURRENTLY, hiding binsort's ~25 us of
// sub-occupancy latency under proj's MFMA work instead of serializing it.
// ---------------------------------------------------------------------------
__global__ __launch_bounds__(256) void fused_kernel(
    const float* __restrict__ X, const float* __restrict__ W,
    const float* __restrict__ att,
    const unsigned* __restrict__ slab, const int* __restrict__ bin_cursor,
    ushort* __restrict__ projT, float* __restrict__ s_src, float* __restrict__ s_tgt,
    ushort* __restrict__ csr, int* __restrict__ offs, int* __restrict__ deg)
{
    __shared__ ushort Wt[128 * WSTR];   // 36.9 KB; binsort blocks alias it

    const int tid = threadIdx.x;

    if (blockIdx.x < NBIN) {
        // ----------------------- binsort part ----------------------------
        int*    cnt2 = (int*)Wt;                 // 256 ints @ 0
        int*    ex   = cnt2 + 256;               // 256 ints @ 1 KB
        int*    wsum = ex + 256;                 // 4 ints   @ 2 KB
        ushort* stgt = (ushort*)(wsum + 8);      // 10 KB    @ 2080 B (fits 36.9 KB)

        const int b = blockIdx.x;
        const int t = tid;
        const int lane = t & 63;
        const int wid  = t >> 6;
        int n_e = bin_cursor[b];
        n_e = (n_e < BINCAP) ? n_e : BINCAP;

        cnt2[t] = 0;
        __syncthreads();

        unsigned pk[20];                   // (tgt<<16)|(rank<<8)|node8
        int npk = 0;
        for (int i = t; i < n_e; i += 256) {
            unsigned v = slab[b * BINCAP + i];
            int node8 = v & 255u;
            int r = atomicAdd(&cnt2[node8], 1);
            r = (r < 255) ? r : 255;
            pk[npk++] = (v & 0xFFFF0000u) | ((unsigned)r << 8) | (unsigned)node8;
        }
        __syncthreads();

        // wave-level inclusive scan over 64 lanes (shuffles unconditional)
        const int v = cnt2[t];
        int x = v;
#pragma unroll
        for (int off = 1; off < 64; off <<= 1) {
            int y = __shfl_up(x, off);
            x += (lane >= off) ? y : 0;
        }
        if (lane == 63) wsum[wid] = x;
        __syncthreads();
        int add = 0;
#pragma unroll
        for (int w = 0; w < 4; ++w) add += (w < wid) ? wsum[w] : 0;
        const int myex = x + add - v;       // exclusive prefix
        const int mycnt = v;
        ex[t] = myex;
        __syncthreads();

        for (int j = 0; j < npk; ++j) {
            unsigned pv = pk[j];
            int lpos = ex[pv & 255u] + (int)((pv >> 8) & 255u);
            if (lpos < BINCAP) stgt[lpos] = (ushort)(pv >> 16);
        }
        __syncthreads();

        for (int i = t; i < n_e; i += 256) csr[b * BINCAP + i] = stgt[i];
        int node = b * 256 + t;
        if (node < N_NODES) {
            offs[node] = b * BINCAP + myex;
            deg[node]  = mycnt;
        }
        return;
    }

    // ------------------------- proj part ---------------------------------
    for (int idx = tid; idx < 64 * 128; idx += 256) {
        int kp = idx >> 7;
        int c  = idx & 127;
        float w0 = W[(2 * kp) * PROJ_DIM + c];
        float w1 = W[(2 * kp + 1) * PROJ_DIM + c];
        unsigned pr = (unsigned)f32_to_bf16(w0) | ((unsigned)f32_to_bf16(w1) << 16);
        *(unsigned*)&Wt[c * WSTR + 2 * kp] = pr;
    }
    __syncthreads();

    const int wv   = tid >> 6;
    const int lane = tid & 63;
    const int m = lane & 15;
    const int q = lane >> 4;
    const int rbase = (blockIdx.x - NBIN) * 128;

    int arow0 = rbase + wv * 32 + m;
    int arow1 = arow0 + 16;
    arow0 = (arow0 < N_NODES) ? arow0 : N_NODES - 1;
    arow1 = (arow1 < N_NODES) ? arow1 : N_NODES - 1;
    const long long xb0 = (long long)arow0 * IN_DIM;
    const long long xb1 = (long long)arow1 * IN_DIM;

    f32x4 acc[2][8];
#pragma unroll
    for (int rt = 0; rt < 2; ++rt)
#pragma unroll
        for (int ct = 0; ct < 8; ++ct) acc[rt][ct] = (f32x4){0.f, 0.f, 0.f, 0.f};

#pragma unroll
    for (int ks = 0; ks < 4; ++ks) {
        const int k0 = ks * 32 + q * 8;
        float4 a0lo = *(const float4*)&X[xb0 + k0];
        float4 a0hi = *(const float4*)&X[xb0 + k0 + 4];
        float4 a1lo = *(const float4*)&X[xb1 + k0];
        float4 a1hi = *(const float4*)&X[xb1 + k0 + 4];
        bf16x8 afrag0 = cvt8(a0lo, a0hi);
        bf16x8 afrag1 = cvt8(a1lo, a1hi);
#pragma unroll
        for (int ct = 0; ct < 8; ++ct) {
            bf16x8 bfrag = *(const bf16x8*)&Wt[(ct * 16 + m) * WSTR + k0];
            acc[0][ct] = __builtin_amdgcn_mfma_f32_16x16x32_bf16(afrag0, bfrag, acc[0][ct], 0, 0, 0);
            acc[1][ct] = __builtin_amdgcn_mfma_f32_16x16x32_bf16(afrag1, bfrag, acc[1][ct], 0, 0, 0);
        }
    }

    const float as_lo = att[m],      as_hi = att[m + 16];
    const float at_lo = att[32 + m], at_hi = att[48 + m];

#pragma unroll
    for (int rt = 0; rt < 2; ++rt) {
        const int rowb = rbase + wv * 32 + rt * 16 + q * 4;
#pragma unroll
        for (int r = 0; r < 4; ++r) {
            const int row = rowb + r;
            float cl[4], ch[4];
#pragma unroll
            for (int h = 0; h < 4; ++h) {
                cl[h] = acc[rt][2 * h][r];
                ch[h] = acc[rt][2 * h + 1][r];
            }
            if (row < N_NODES) {
                ushort4 plo, phi;
                plo.x = f32_to_bf16(cl[0]); plo.y = f32_to_bf16(cl[1]);
                plo.z = f32_to_bf16(cl[2]); plo.w = f32_to_bf16(cl[3]);
                phi.x = f32_to_bf16(ch[0]); phi.y = f32_to_bf16(ch[1]);
                phi.z = f32_to_bf16(ch[2]); phi.w = f32_to_bf16(ch[3]);
                *(ushort4*)&projT[(long long)row * PROJ_DIM + m * 4] = plo;
                *(ushort4*)&projT[(long long)row * PROJ_DIM + (m + 16) * 4] = phi;
            }
            float ps[4], pt[4];
#pragma unroll
            for (int h = 0; h < 4; ++h) {
                ps[h] = cl[h] * as_lo + ch[h] * as_hi;
                pt[h] = cl[h] * at_lo + ch[h] * at_hi;
            }
#pragma unroll
            for (int off = 8; off > 0; off >>= 1) {
#pragma unroll
                for (int h = 0; h < 4; ++h) {
                    ps[h] += __shfl_down(ps[h], off, 16);
                    pt[h] += __shfl_down(pt[h], off, 16);
                }
            }
            if (m == 0 && row < N_NODES) {
                *(float4*)&s_src[row * N_HEADS] = make_float4(ps[0], ps[1], ps[2], ps[3]);
                *(float4*)&s_tgt[row * N_HEADS] = make_float4(pt[0], pt[1], pt[2], pt[3]);
            }
        }
    }
}

// ---------------------------------------------------------------------------
// K3: gather — EXACT R1 structure (best measured). One WAVE per node,
// barrier-free, LDS-free, unified 16-slot pass, UNCONDITIONAL loads
// (R2 proved exec-masking them regresses), tail zeroed on alphas only.
// ---------------------------------------------------------------------------
__global__ __launch_bounds__(256) void gather_kernel(
    const int* __restrict__ deg, const int* __restrict__ offs,
    const ushort* __restrict__ csr,
    const float* __restrict__ s_src, const float* __restrict__ s_tgt,
    const ushort* __restrict__ projT, float* __restrict__ out)
{
    const int wv   = threadIdx.x >> 6;
    const int lane = threadIdx.x & 63;
    const int node = blockIdx.x * 4 + wv;  // N_NODES = 12500*4

    int n = deg[node];
    n = (n < MAXDEG) ? n : MAXDEG;
    const int o = offs[node];

    int mytgt = 0, myA01 = 0, myA23 = 0;
    if (lane < n) {
        int tgt = csr[o + lane];                            // coalesced ushort
        float4 ss = *(const float4*)&s_src[node * N_HEADS]; // wave-uniform
        float4 st = *(const float4*)&s_tgt[tgt * N_HEADS];  // parallel gather

        float sc[4] = { ss.x + st.x, ss.y + st.y, ss.z + st.z, ss.w + st.w };
        float mx = -1e30f;
#pragma unroll
        for (int h = 0; h < 4; ++h) {
            sc[h] = (sc[h] > 0.0f) ? sc[h] : 0.01f * sc[h];  // leaky_relu
            mx = fmaxf(mx, sc[h]);
        }
        float sum = 0.0f;
#pragma unroll
        for (int h = 0; h < 4; ++h) {
            sc[h] = __expf(sc[h] - mx);
            sum += sc[h];
        }
        float inv = 0.25f / sum;     // softmax normalize * head-mean

        h2 a01, a23;
        a01.x = (_Float16)(sc[0] * inv);
        a01.y = (_Float16)(sc[1] * inv);
        a23.x = (_Float16)(sc[2] * inv);
        a23.y = (_Float16)(sc[3] * inv);
        mytgt = tgt;
        myA01 = __builtin_bit_cast(int, a01);
        myA23 = __builtin_bit_cast(int, a23);
    }
    // no barrier: producers and consumers are the same wave

    const int d    = lane & 31;
    const int half = lane >> 5;

    float acc0 = 0.0f, acc1 = 0.0f, acc2 = 0.0f, acc3 = 0.0f;

    // Unified pass: 16 edge slots per iteration (8 per half), 8 outstanding
    // projT gathers per lane, tail handled by clamp+zero on the ALPHAS only.
    for (int j = 0; j < n; j += 16) {
        int tg[8], ea[8], eb[8];
#pragma unroll
        for (int u = 0; u < 8; ++u) {
            int sl = j + 2 * u + half;
            bool ok = sl < n;
            int slc = ok ? sl : 0;
            int tgv = __shfl(mytgt, slc);   // unconditional, full EXEC
            int eav = __shfl(myA01, slc);
            int ebv = __shfl(myA23, slc);
            tg[u] = tgv;
            ea[u] = ok ? eav : 0;
            eb[u] = ok ? ebv : 0;
        }
        ushort4 p[8];
#pragma unroll
        for (int u = 0; u < 8; ++u)
            p[u] = *(const ushort4*)&projT[(long long)tg[u] * PROJ_DIM + d * 4];
#pragma unroll
        for (int u = 0; u < 8; ++u) {
            h2 a = __builtin_bit_cast(h2, ea[u]);
            h2 b = __builtin_bit_cast(h2, eb[u]);
            float* accp = (u & 1) ? ((u & 2) ? &acc3 : &acc1)
                                  : ((u & 2) ? &acc2 : &acc0);
            float tt = *accp;
            tt = fmaf((float)a.x, bf16_to_f32(p[u].x), tt);
            tt = fmaf((float)a.y, bf16_to_f32(p[u].y), tt);
            tt = fmaf((float)b.x, bf16_to_f32(p[u].z), tt);
            tt = fmaf((float)b.y, bf16_to_f32(p[u].w), tt);
            *accp = tt;
        }
    }

    float acc = (acc0 + acc1) + (acc2 + acc3);
    acc += __shfl_down(acc, 32);      // combine the two halves (width 64)
    if (lane < 32) out[node * OUT_DIM + d] = acc;
}

extern "C" void kernel_launch(void* const* d_in, const int* in_sizes, int n_in,
                              void* d_out, int out_size, void* d_ws, size_t ws_size,
                              hipStream_t stream) {
    const float* X   = (const float*)d_in[0];
    const int*   ei  = (const int*)d_in[1];
    const float* W   = (const float*)d_in[2];
    const float* att = (const float*)d_in[3];
    float* out = (float*)d_out;

    // workspace layout, total ~20.8 MB
    char* p = (char*)d_ws;
    ushort* projT   = (ushort*)p;   p += (size_t)N_NODES * PROJ_DIM * 2;  // 12.8 MB
    float* s_src    = (float*)p;    p += (size_t)N_NODES * N_HEADS * 4;   // 0.8 MB
    float* s_tgt    = (float*)p;    p += (size_t)N_NODES * N_HEADS * 4;   // 0.8 MB
    unsigned* slab  = (unsigned*)p; p += (size_t)NBIN * BINCAP * 4;       // 3.92 MB
    ushort* csr     = (ushort*)p;   p += (size_t)NBIN * BINCAP * 2;       // 1.96 MB
    int* offs       = (int*)p;      p += (size_t)N_NODES * 4;             // 0.2 MB
    int* deg        = (int*)p;      p += (size_t)N_NODES * 4;             // 0.2 MB
    int* bin_cursor = (int*)p;      p += 256 * 4;

    (void)hipMemsetAsync(bin_cursor, 0, 256 * sizeof(int), stream);

    partition_kernel<<<PART_BLKS, 256, 0, stream>>>(ei, bin_cursor, slab);

    fused_kernel<<<FUSE_BLKS, 256, 0, stream>>>(
        X, W, att, slab, bin_cursor, projT, s_src, s_tgt, csr, offs, deg);

    gather_kernel<<<N_NODES / 4, 256, 0, stream>>>(
        deg, offs, csr, s_src, s_tgt, projT, out);
}

// Round 6
// 136.780 us; speedup vs baseline: 1.1533x; 1.0387x over previous
//
#include <hip/hip_runtime.h>
#include <math.h>

#define N_NODES 50000
#define N_EDGES 800000
#define IN_DIM 128
#define N_HEADS 4
#define OUT_DIM 32
#define PROJ_DIM 128   // N_HEADS * OUT_DIM
#define WSTR 144       // Wt LDS row stride in shorts (288 B, 16B-aligned)

#define NBIN 196       // ceil(50000/256): bin = src >> 8
#define BINCAP 5000    // edges per bin region (mean 4096, sigma ~64 -> 14 sigma)
#define MAXDEG 64      // gather clamp (max expected deg ~38 for Poisson(16))

#define PROJ_BLKS 391                    // ceil(50000/128), 128 rows/block
#define PART_BLKS 391                    // 2048 edges per block
#define FUSE_BLKS (NBIN + PROJ_BLKS)     // K2: binsort blocks first, then proj

typedef short bf16x8 __attribute__((ext_vector_type(8)));
typedef float f32x4  __attribute__((ext_vector_type(4)));
typedef _Float16 h2  __attribute__((ext_vector_type(2)));

// fp32 -> bf16 bits with round-to-nearest-even (used for MFMA input staging)
__device__ __forceinline__ ushort f32_to_bf16(float f) {
    unsigned u = __float_as_uint(f);
    unsigned r = u + 0x7fffu + ((u >> 16) & 1u);
    return (ushort)(r >> 16);
}

__device__ __forceinline__ bf16x8 cvt8(float4 a, float4 b) {
    bf16x8 r;
    r[0] = (short)f32_to_bf16(a.x); r[1] = (short)f32_to_bf16(a.y);
    r[2] = (short)f32_to_bf16(a.z); r[3] = (short)f32_to_bf16(a.w);
    r[4] = (short)f32_to_bf16(b.x); r[5] = (short)f32_to_bf16(b.y);
    r[6] = (short)f32_to_bf16(b.z); r[7] = (short)f32_to_bf16(b.w);
    return r;
}

// f32 -> f16 bits (RTE). projT is stored as f16 now: gather consumes it via
// v_dot2_f32_f16 / v_fma_mix (no per-element cvt), and f16's 10-bit mantissa
// beats bf16's 7 bits for these O(1) values.
__device__ __forceinline__ ushort f32_to_f16(float f) {
    return __builtin_bit_cast(ushort, (_Float16)f);
}

// ---------------------------------------------------------------------------
// K1: partition (unchanged from R5). 2048 edges/block, LDS histogram over
// 196 coarse bins (src>>8), 196 returning global atomics/block, packed
// slab stores.
// ---------------------------------------------------------------------------
__global__ __launch_bounds__(256) void partition_kernel(
    const int* __restrict__ ei, int* __restrict__ bin_cursor,
    unsigned* __restrict__ slab)
{
    __shared__ int cnt[256];
    __shared__ int gbase[256];

    const int tid = threadIdx.x;

    for (int t = tid; t < NBIN; t += 256) cnt[t] = 0;
    __syncthreads();

    const int ebase = blockIdx.x * 2048;
    unsigned srcv[8], tgtv[8];
    int rank[8];
#pragma unroll
    for (int i = 0; i < 8; ++i) {
        int e = ebase + i * 256 + tid;
        bool ok = e < N_EDGES;
        srcv[i] = ok ? (unsigned)ei[e] : 0u;
        tgtv[i] = ok ? (unsigned)ei[N_EDGES + e] : 0u;
        rank[i] = ok ? atomicAdd(&cnt[srcv[i] >> 8], 1) : -1;
    }
    __syncthreads();

    for (int t = tid; t < NBIN; t += 256)
        gbase[t] = atomicAdd(&bin_cursor[t], cnt[t]);   // 196/block global
    __syncthreads();

#pragma unroll
    for (int i = 0; i < 8; ++i) {
        if (rank[i] >= 0) {
            int bin = srcv[i] >> 8;
            int p = gbase[bin] + rank[i];
            if (p < BINCAP)
                slab[bin * BINCAP + p] = (tgtv[i] << 16) | (srcv[i] & 255u);
        }
    }
}

// ---------------------------------------------------------------------------
// K2: proj + binsort FUSED by block specialization (R5 structure, proven).
//  blocks [0, NBIN): binsort one bin each (LDS aliased onto Wt).
//  blocks [NBIN, FUSE_BLKS): proj = X @ W via bf16 MFMA 16x16x32.
// CHANGE vs R5: projT epilogue stores f16 bits instead of bf16.
// ---------------------------------------------------------------------------
__global__ __launch_bounds__(256) void fused_kernel(
    const float* __restrict__ X, const float* __restrict__ W,
    const float* __restrict__ att,
    const unsigned* __restrict__ slab, const int* __restrict__ bin_cursor,
    ushort* __restrict__ projT, float* __restrict__ s_src, float* __restrict__ s_tgt,
    ushort* __restrict__ csr, int* __restrict__ offs, int* __restrict__ deg)
{
    __shared__ ushort Wt[128 * WSTR];   // 36.9 KB; binsort blocks alias it

    const int tid = threadIdx.x;

    if (blockIdx.x < NBIN) {
        // ----------------------- binsort part ----------------------------
        int*    cnt2 = (int*)Wt;                 // 256 ints @ 0
        int*    ex   = cnt2 + 256;               // 256 ints @ 1 KB
        int*    wsum = ex + 256;                 // 4 ints   @ 2 KB
        ushort* stgt = (ushort*)(wsum + 8);      // 10 KB    @ 2080 B (fits 36.9 KB)

        const int b = blockIdx.x;
        const int t = tid;
        const int lane = t & 63;
        const int wid  = t >> 6;
        int n_e = bin_cursor[b];
        n_e = (n_e < BINCAP) ? n_e : BINCAP;

        cnt2[t] = 0;
        __syncthreads();

        unsigned pk[20];                   // (tgt<<16)|(rank<<8)|node8
        int npk = 0;
        for (int i = t; i < n_e; i += 256) {
            unsigned v = slab[b * BINCAP + i];
            int node8 = v & 255u;
            int r = atomicAdd(&cnt2[node8], 1);
            r = (r < 255) ? r : 255;
            pk[npk++] = (v & 0xFFFF0000u) | ((unsigned)r << 8) | (unsigned)node8;
        }
        __syncthreads();

        // wave-level inclusive scan over 64 lanes (shuffles unconditional)
        const int v = cnt2[t];
        int x = v;
#pragma unroll
        for (int off = 1; off < 64; off <<= 1) {
            int y = __shfl_up(x, off);
            x += (lane >= off) ? y : 0;
        }
        if (lane == 63) wsum[wid] = x;
        __syncthreads();
        int add = 0;
#pragma unroll
        for (int w = 0; w < 4; ++w) add += (w < wid) ? wsum[w] : 0;
        const int myex = x + add - v;       // exclusive prefix
        const int mycnt = v;
        ex[t] = myex;
        __syncthreads();

        for (int j = 0; j < npk; ++j) {
            unsigned pv = pk[j];
            int lpos = ex[pv & 255u] + (int)((pv >> 8) & 255u);
            if (lpos < BINCAP) stgt[lpos] = (ushort)(pv >> 16);
        }
        __syncthreads();

        for (int i = t; i < n_e; i += 256) csr[b * BINCAP + i] = stgt[i];
        int node = b * 256 + t;
        if (node < N_NODES) {
            offs[node] = b * BINCAP + myex;
            deg[node]  = mycnt;
        }
        return;
    }

    // ------------------------- proj part ---------------------------------
    for (int idx = tid; idx < 64 * 128; idx += 256) {
        int kp = idx >> 7;
        int c  = idx & 127;
        float w0 = W[(2 * kp) * PROJ_DIM + c];
        float w1 = W[(2 * kp + 1) * PROJ_DIM + c];
        unsigned pr = (unsigned)f32_to_bf16(w0) | ((unsigned)f32_to_bf16(w1) << 16);
        *(unsigned*)&Wt[c * WSTR + 2 * kp] = pr;
    }
    __syncthreads();

    const int wv   = tid >> 6;
    const int lane = tid & 63;
    const int m = lane & 15;
    const int q = lane >> 4;
    const int rbase = (blockIdx.x - NBIN) * 128;

    int arow0 = rbase + wv * 32 + m;
    int arow1 = arow0 + 16;
    arow0 = (arow0 < N_NODES) ? arow0 : N_NODES - 1;
    arow1 = (arow1 < N_NODES) ? arow1 : N_NODES - 1;
    const long long xb0 = (long long)arow0 * IN_DIM;
    const long long xb1 = (long long)arow1 * IN_DIM;

    f32x4 acc[2][8];
#pragma unroll
    for (int rt = 0; rt < 2; ++rt)
#pragma unroll
        for (int ct = 0; ct < 8; ++ct) acc[rt][ct] = (f32x4){0.f, 0.f, 0.f, 0.f};

#pragma unroll
    for (int ks = 0; ks < 4; ++ks) {
        const int k0 = ks * 32 + q * 8;
        float4 a0lo = *(const float4*)&X[xb0 + k0];
        float4 a0hi = *(const float4*)&X[xb0 + k0 + 4];
        float4 a1lo = *(const float4*)&X[xb1 + k0];
        float4 a1hi = *(const float4*)&X[xb1 + k0 + 4];
        bf16x8 afrag0 = cvt8(a0lo, a0hi);
        bf16x8 afrag1 = cvt8(a1lo, a1hi);
#pragma unroll
        for (int ct = 0; ct < 8; ++ct) {
            bf16x8 bfrag = *(const bf16x8*)&Wt[(ct * 16 + m) * WSTR + k0];
            acc[0][ct] = __builtin_amdgcn_mfma_f32_16x16x32_bf16(afrag0, bfrag, acc[0][ct], 0, 0, 0);
            acc[1][ct] = __builtin_amdgcn_mfma_f32_16x16x32_bf16(afrag1, bfrag, acc[1][ct], 0, 0, 0);
        }
    }

    const float as_lo = att[m],      as_hi = att[m + 16];
    const float at_lo = att[32 + m], at_hi = att[48 + m];

#pragma unroll
    for (int rt = 0; rt < 2; ++rt) {
        const int rowb = rbase + wv * 32 + rt * 16 + q * 4;
#pragma unroll
        for (int r = 0; r < 4; ++r) {
            const int row = rowb + r;
            float cl[4], ch[4];
#pragma unroll
            for (int h = 0; h < 4; ++h) {
                cl[h] = acc[rt][2 * h][r];
                ch[h] = acc[rt][2 * h + 1][r];
            }
            if (row < N_NODES) {
                ushort4 plo, phi;
                plo.x = f32_to_f16(cl[0]); plo.y = f32_to_f16(cl[1]);
                plo.z = f32_to_f16(cl[2]); plo.w = f32_to_f16(cl[3]);
                phi.x = f32_to_f16(ch[0]); phi.y = f32_to_f16(ch[1]);
                phi.z = f32_to_f16(ch[2]); phi.w = f32_to_f16(ch[3]);
                *(ushort4*)&projT[(long long)row * PROJ_DIM + m * 4] = plo;
                *(ushort4*)&projT[(long long)row * PROJ_DIM + (m + 16) * 4] = phi;
            }
            float ps[4], pt[4];
#pragma unroll
            for (int h = 0; h < 4; ++h) {
                ps[h] = cl[h] * as_lo + ch[h] * as_hi;
                pt[h] = cl[h] * at_lo + ch[h] * at_hi;
            }
#pragma unroll
            for (int off = 8; off > 0; off >>= 1) {
#pragma unroll
                for (int h = 0; h < 4; ++h) {
                    ps[h] += __shfl_down(ps[h], off, 16);
                    pt[h] += __shfl_down(pt[h], off, 16);
                }
            }
            if (m == 0 && row < N_NODES) {
                *(float4*)&s_src[row * N_HEADS] = make_float4(ps[0], ps[1], ps[2], ps[3]);
                *(float4*)&s_tgt[row * N_HEADS] = make_float4(pt[0], pt[1], pt[2], pt[3]);
            }
        }
    }
}

// ---------------------------------------------------------------------------
// K3: gather — R5 schedule (proven best), accumulate rewritten on f16:
//   per slot: 2x v_dot2_f32_f16 (or v_fma_mix fallback) replaces
//   4x bf16->f32 shift + 4x fmaf. Cuts the accumulate VALU work 4x.
//   Loads are uint2 (8 B, same bytes as before). Everything else identical.
// ---------------------------------------------------------------------------
__global__ __launch_bounds__(256) void gather_kernel(
    const int* __restrict__ deg, const int* __restrict__ offs,
    const ushort* __restrict__ csr,
    const float* __restrict__ s_src, const float* __restrict__ s_tgt,
    const ushort* __restrict__ projT, float* __restrict__ out)
{
    const int wv   = threadIdx.x >> 6;
    const int lane = threadIdx.x & 63;
    const int node = blockIdx.x * 4 + wv;  // N_NODES = 12500*4

    int n = deg[node];
    n = (n < MAXDEG) ? n : MAXDEG;
    const int o = offs[node];

    int mytgt = 0, myA01 = 0, myA23 = 0;
    if (lane < n) {
        int tgt = csr[o + lane];                            // coalesced ushort
        float4 ss = *(const float4*)&s_src[node * N_HEADS]; // wave-uniform
        float4 st = *(const float4*)&s_tgt[tgt * N_HEADS];  // parallel gather

        float sc[4] = { ss.x + st.x, ss.y + st.y, ss.z + st.z, ss.w + st.w };
        float mx = -1e30f;
#pragma unroll
        for (int h = 0; h < 4; ++h) {
            sc[h] = (sc[h] > 0.0f) ? sc[h] : 0.01f * sc[h];  // leaky_relu
            mx = fmaxf(mx, sc[h]);
        }
        float sum = 0.0f;
#pragma unroll
        for (int h = 0; h < 4; ++h) {
            sc[h] = __expf(sc[h] - mx);
            sum += sc[h];
        }
        float inv = 0.25f / sum;     // softmax normalize * head-mean

        h2 a01, a23;
        a01.x = (_Float16)(sc[0] * inv);
        a01.y = (_Float16)(sc[1] * inv);
        a23.x = (_Float16)(sc[2] * inv);
        a23.y = (_Float16)(sc[3] * inv);
        mytgt = tgt;
        myA01 = __builtin_bit_cast(int, a01);
        myA23 = __builtin_bit_cast(int, a23);
    }
    // no barrier: producers and consumers are the same wave

    const int d    = lane & 31;
    const int half = lane >> 5;

    float acc0 = 0.0f, acc1 = 0.0f, acc2 = 0.0f, acc3 = 0.0f;

    // Unified pass: 16 edge slots per iteration (8 per half), 8 outstanding
    // projT gathers per lane, tail handled by clamp+zero on the ALPHAS only.
    for (int j = 0; j < n; j += 16) {
        int tg[8], ea[8], eb[8];
#pragma unroll
        for (int u = 0; u < 8; ++u) {
            int sl = j + 2 * u + half;
            bool ok = sl < n;
            int slc = ok ? sl : 0;
            int tgv = __shfl(mytgt, slc);   // unconditional, full EXEC
            int eav = __shfl(myA01, slc);
            int ebv = __shfl(myA23, slc);
            tg[u] = tgv;
            ea[u] = ok ? eav : 0;
            eb[u] = ok ? ebv : 0;
        }
        uint2 p[8];
#pragma unroll
        for (int u = 0; u < 8; ++u)
            p[u] = *(const uint2*)&projT[(long long)tg[u] * PROJ_DIM + d * 4];
#pragma unroll
        for (int u = 0; u < 8; ++u) {
            h2 a  = __builtin_bit_cast(h2, ea[u]);
            h2 b  = __builtin_bit_cast(h2, eb[u]);
            h2 lo = __builtin_bit_cast(h2, p[u].x);
            h2 hi = __builtin_bit_cast(h2, p[u].y);
            float* accp = (u & 1) ? ((u & 2) ? &acc3 : &acc1)
                                  : ((u & 2) ? &acc2 : &acc0);
            float tt = *accp;
#if __has_builtin(__builtin_amdgcn_fdot2)
            tt = __builtin_amdgcn_fdot2(a, lo, tt, false);   // v_dot2_f32_f16
            tt = __builtin_amdgcn_fdot2(b, hi, tt, false);
#else
            tt = fmaf((float)a.x, (float)lo.x, tt);          // v_fma_mix_f32
            tt = fmaf((float)a.y, (float)lo.y, tt);
            tt = fmaf((float)b.x, (float)hi.x, tt);
            tt = fmaf((float)b.y, (float)hi.y, tt);
#endif
            *accp = tt;
        }
    }

    float acc = (acc0 + acc1) + (acc2 + acc3);
    acc += __shfl_down(acc, 32);      // combine the two halves (width 64)
    if (lane < 32) out[node * OUT_DIM + d] = acc;
}

extern "C" void kernel_launch(void* const* d_in, const int* in_sizes, int n_in,
                              void* d_out, int out_size, void* d_ws, size_t ws_size,
                              hipStream_t stream) {
    const float* X   = (const float*)d_in[0];
    const int*   ei  = (const int*)d_in[1];
    const float* W   = (const float*)d_in[2];
    const float* att = (const float*)d_in[3];
    float* out = (float*)d_out;

    // workspace layout, total ~20.8 MB
    char* p = (char*)d_ws;
    ushort* projT   = (ushort*)p;   p += (size_t)N_NODES * PROJ_DIM * 2;  // 12.8 MB
    float* s_src    = (float*)p;    p += (size_t)N_NODES * N_HEADS * 4;   // 0.8 MB
    float* s_tgt    = (float*)p;    p += (size_t)N_NODES * N_HEADS * 4;   // 0.8 MB
    unsigned* slab  = (unsigned*)p; p += (size_t)NBIN * BINCAP * 4;       // 3.92 MB
    ushort* csr     = (ushort*)p;   p += (size_t)NBIN * BINCAP * 2;       // 1.96 MB
    int* offs       = (int*)p;      p += (size_t)N_NODES * 4;             // 0.2 MB
    int* deg        = (int*)p;      p += (size_t)N_NODES * 4;             // 0.2 MB
    int* bin_cursor = (int*)p;      p += 256 * 4;

    (void)hipMemsetAsync(bin_cursor, 0, 256 * sizeof(int), stream);

    partition_kernel<<<PART_BLKS, 256, 0, stream>>>(ei, bin_cursor, slab);

    fused_kernel<<<FUSE_BLKS, 256, 0, stream>>>(
        X, W, att, slab, bin_cursor, projT, s_src, s_tgt, csr, offs, deg);

    gather_kernel<<<N_NODES / 4, 256, 0, stream>>>(
        deg, offs, csr, s_src, s_tgt, projT, out);
}

// Round 7
// 136.289 us; speedup vs baseline: 1.1575x; 1.0036x over previous
//
#include <hip/hip_runtime.h>
#include <math.h>

#define N_NODES 50000
#define N_EDGES 800000
#define IN_DIM 128
#define N_HEADS 4
#define OUT_DIM 32
#define PROJ_DIM 128   // N_HEADS * OUT_DIM
#define WSTR 144       // Wt LDS row stride in shorts (288 B, 16B-aligned)

#define NBIN 196       // ceil(50000/256): bin = src >> 8
#define BINCAP 5000    // edges per bin region (mean 4096, sigma ~64 -> 14 sigma)
#define MAXDEG 64      // gather clamp (max expected deg ~38 for Poisson(16))

#define PROJ_BLKS 391                    // ceil(50000/128), 128 rows/block
#define PART_BLKS 391                    // 2048 edges per block
#define FUSE_BLKS (NBIN + PROJ_BLKS)     // K2: binsort blocks first, then proj

typedef short bf16x8 __attribute__((ext_vector_type(8)));
typedef float f32x4  __attribute__((ext_vector_type(4)));
typedef _Float16 h2  __attribute__((ext_vector_type(2)));

// fp32 -> bf16 bits with round-to-nearest-even (used for MFMA input staging)
__device__ __forceinline__ ushort f32_to_bf16(float f) {
    unsigned u = __float_as_uint(f);
    unsigned r = u + 0x7fffu + ((u >> 16) & 1u);
    return (ushort)(r >> 16);
}

__device__ __forceinline__ bf16x8 cvt8(float4 a, float4 b) {
    bf16x8 r;
    r[0] = (short)f32_to_bf16(a.x); r[1] = (short)f32_to_bf16(a.y);
    r[2] = (short)f32_to_bf16(a.z); r[3] = (short)f32_to_bf16(a.w);
    r[4] = (short)f32_to_bf16(b.x); r[5] = (short)f32_to_bf16(b.y);
    r[6] = (short)f32_to_bf16(b.z); r[7] = (short)f32_to_bf16(b.w);
    return r;
}

// f32 -> f16 bits (RTE). projT stored as f16: gather consumes via
// v_dot2_f32_f16, and f16's 10-bit mantissa beats bf16 for these O(1) values.
__device__ __forceinline__ ushort f32_to_f16(float f) {
    return __builtin_bit_cast(ushort, (_Float16)f);
}

// ---------------------------------------------------------------------------
// K1: partition (unchanged from R5/R6). 2048 edges/block, LDS histogram over
// 196 coarse bins (src>>8), 196 returning global atomics/block, packed
// slab stores.
// ---------------------------------------------------------------------------
__global__ __launch_bounds__(256) void partition_kernel(
    const int* __restrict__ ei, int* __restrict__ bin_cursor,
    unsigned* __restrict__ slab)
{
    __shared__ int cnt[256];
    __shared__ int gbase[256];

    const int tid = threadIdx.x;

    for (int t = tid; t < NBIN; t += 256) cnt[t] = 0;
    __syncthreads();

    const int ebase = blockIdx.x * 2048;
    unsigned srcv[8], tgtv[8];
    int rank[8];
#pragma unroll
    for (int i = 0; i < 8; ++i) {
        int e = ebase + i * 256 + tid;
        bool ok = e < N_EDGES;
        srcv[i] = ok ? (unsigned)ei[e] : 0u;
        tgtv[i] = ok ? (unsigned)ei[N_EDGES + e] : 0u;
        rank[i] = ok ? atomicAdd(&cnt[srcv[i] >> 8], 1) : -1;
    }
    __syncthreads();

    for (int t = tid; t < NBIN; t += 256)
        gbase[t] = atomicAdd(&bin_cursor[t], cnt[t]);   // 196/block global
    __syncthreads();

#pragma unroll
    for (int i = 0; i < 8; ++i) {
        if (rank[i] >= 0) {
            int bin = srcv[i] >> 8;
            int p = gbase[bin] + rank[i];
            if (p < BINCAP)
                slab[bin * BINCAP + p] = (tgtv[i] << 16) | (srcv[i] & 255u);
        }
    }
}

// ---------------------------------------------------------------------------
// K2: proj + binsort FUSED by block specialization (unchanged from R6).
//  blocks [0, NBIN): binsort one bin each (LDS aliased onto Wt).
//  blocks [NBIN, FUSE_BLKS): proj = X @ W via bf16 MFMA 16x16x32; projT
//  epilogue stores f16 bits.
// ---------------------------------------------------------------------------
__global__ __launch_bounds__(256) void fused_kernel(
    const float* __restrict__ X, const float* __restrict__ W,
    const float* __restrict__ att,
    const unsigned* __restrict__ slab, const int* __restrict__ bin_cursor,
    ushort* __restrict__ projT, float* __restrict__ s_src, float* __restrict__ s_tgt,
    ushort* __restrict__ csr, int* __restrict__ offs, int* __restrict__ deg)
{
    __shared__ ushort Wt[128 * WSTR];   // 36.9 KB; binsort blocks alias it

    const int tid = threadIdx.x;

    if (blockIdx.x < NBIN) {
        // ----------------------- binsort part ----------------------------
        int*    cnt2 = (int*)Wt;                 // 256 ints @ 0
        int*    ex   = cnt2 + 256;               // 256 ints @ 1 KB
        int*    wsum = ex + 256;                 // 4 ints   @ 2 KB
        ushort* stgt = (ushort*)(wsum + 8);      // 10 KB    @ 2080 B (fits 36.9 KB)

        const int b = blockIdx.x;
        const int t = tid;
        const int lane = t & 63;
        const int wid  = t >> 6;
        int n_e = bin_cursor[b];
        n_e = (n_e < BINCAP) ? n_e : BINCAP;

        cnt2[t] = 0;
        __syncthreads();

        unsigned pk[20];                   // (tgt<<16)|(rank<<8)|node8
        int npk = 0;
        for (int i = t; i < n_e; i += 256) {
            unsigned v = slab[b * BINCAP + i];
            int node8 = v & 255u;
            int r = atomicAdd(&cnt2[node8], 1);
            r = (r < 255) ? r : 255;
            pk[npk++] = (v & 0xFFFF0000u) | ((unsigned)r << 8) | (unsigned)node8;
        }
        __syncthreads();

        // wave-level inclusive scan over 64 lanes (shuffles unconditional)
        const int v = cnt2[t];
        int x = v;
#pragma unroll
        for (int off = 1; off < 64; off <<= 1) {
            int y = __shfl_up(x, off);
            x += (lane >= off) ? y : 0;
        }
        if (lane == 63) wsum[wid] = x;
        __syncthreads();
        int add = 0;
#pragma unroll
        for (int w = 0; w < 4; ++w) add += (w < wid) ? wsum[w] : 0;
        const int myex = x + add - v;       // exclusive prefix
        const int mycnt = v;
        ex[t] = myex;
        __syncthreads();

        for (int j = 0; j < npk; ++j) {
            unsigned pv = pk[j];
            int lpos = ex[pv & 255u] + (int)((pv >> 8) & 255u);
            if (lpos < BINCAP) stgt[lpos] = (ushort)(pv >> 16);
        }
        __syncthreads();

        for (int i = t; i < n_e; i += 256) csr[b * BINCAP + i] = stgt[i];
        int node = b * 256 + t;
        if (node < N_NODES) {
            offs[node] = b * BINCAP + myex;
            deg[node]  = mycnt;
        }
        return;
    }

    // ------------------------- proj part ---------------------------------
    for (int idx = tid; idx < 64 * 128; idx += 256) {
        int kp = idx >> 7;
        int c  = idx & 127;
        float w0 = W[(2 * kp) * PROJ_DIM + c];
        float w1 = W[(2 * kp + 1) * PROJ_DIM + c];
        unsigned pr = (unsigned)f32_to_bf16(w0) | ((unsigned)f32_to_bf16(w1) << 16);
        *(unsigned*)&Wt[c * WSTR + 2 * kp] = pr;
    }
    __syncthreads();

    const int wv   = tid >> 6;
    const int lane = tid & 63;
    const int m = lane & 15;
    const int q = lane >> 4;
    const int rbase = (blockIdx.x - NBIN) * 128;

    int arow0 = rbase + wv * 32 + m;
    int arow1 = arow0 + 16;
    arow0 = (arow0 < N_NODES) ? arow0 : N_NODES - 1;
    arow1 = (arow1 < N_NODES) ? arow1 : N_NODES - 1;
    const long long xb0 = (long long)arow0 * IN_DIM;
    const long long xb1 = (long long)arow1 * IN_DIM;

    f32x4 acc[2][8];
#pragma unroll
    for (int rt = 0; rt < 2; ++rt)
#pragma unroll
        for (int ct = 0; ct < 8; ++ct) acc[rt][ct] = (f32x4){0.f, 0.f, 0.f, 0.f};

#pragma unroll
    for (int ks = 0; ks < 4; ++ks) {
        const int k0 = ks * 32 + q * 8;
        float4 a0lo = *(const float4*)&X[xb0 + k0];
        float4 a0hi = *(const float4*)&X[xb0 + k0 + 4];
        float4 a1lo = *(const float4*)&X[xb1 + k0];
        float4 a1hi = *(const float4*)&X[xb1 + k0 + 4];
        bf16x8 afrag0 = cvt8(a0lo, a0hi);
        bf16x8 afrag1 = cvt8(a1lo, a1hi);
#pragma unroll
        for (int ct = 0; ct < 8; ++ct) {
            bf16x8 bfrag = *(const bf16x8*)&Wt[(ct * 16 + m) * WSTR + k0];
            acc[0][ct] = __builtin_amdgcn_mfma_f32_16x16x32_bf16(afrag0, bfrag, acc[0][ct], 0, 0, 0);
            acc[1][ct] = __builtin_amdgcn_mfma_f32_16x16x32_bf16(afrag1, bfrag, acc[1][ct], 0, 0, 0);
        }
    }

    const float as_lo = att[m],      as_hi = att[m + 16];
    const float at_lo = att[32 + m], at_hi = att[48 + m];

#pragma unroll
    for (int rt = 0; rt < 2; ++rt) {
        const int rowb = rbase + wv * 32 + rt * 16 + q * 4;
#pragma unroll
        for (int r = 0; r < 4; ++r) {
            const int row = rowb + r;
            float cl[4], ch[4];
#pragma unroll
            for (int h = 0; h < 4; ++h) {
                cl[h] = acc[rt][2 * h][r];
                ch[h] = acc[rt][2 * h + 1][r];
            }
            if (row < N_NODES) {
                ushort4 plo, phi;
                plo.x = f32_to_f16(cl[0]); plo.y = f32_to_f16(cl[1]);
                plo.z = f32_to_f16(cl[2]); plo.w = f32_to_f16(cl[3]);
                phi.x = f32_to_f16(ch[0]); phi.y = f32_to_f16(ch[1]);
                phi.z = f32_to_f16(ch[2]); phi.w = f32_to_f16(ch[3]);
                *(ushort4*)&projT[(long long)row * PROJ_DIM + m * 4] = plo;
                *(ushort4*)&projT[(long long)row * PROJ_DIM + (m + 16) * 4] = phi;
            }
            float ps[4], pt[4];
#pragma unroll
            for (int h = 0; h < 4; ++h) {
                ps[h] = cl[h] * as_lo + ch[h] * as_hi;
                pt[h] = cl[h] * at_lo + ch[h] * at_hi;
            }
#pragma unroll
            for (int off = 8; off > 0; off >>= 1) {
#pragma unroll
                for (int h = 0; h < 4; ++h) {
                    ps[h] += __shfl_down(ps[h], off, 16);
                    pt[h] += __shfl_down(pt[h], off, 16);
                }
            }
            if (m == 0 && row < N_NODES) {
                *(float4*)&s_src[row * N_HEADS] = make_float4(ps[0], ps[1], ps[2], ps[3]);
                *(float4*)&s_tgt[row * N_HEADS] = make_float4(pt[0], pt[1], pt[2], pt[3]);
            }
        }
    }
}

// ---------------------------------------------------------------------------
// K3: gather v5 — LDS edge-table broadcast replaces shuffle-broadcast.
//   Prep writes each edge's (tgt, A01, A23, 0) ONCE to a per-wave LDS table
//   (ds_write_b128, contiguous -> conflict-free; dead slots pre-zeroed so
//   alpha=0/tgt=0). The accumulate loop then fetches a slot with ONE
//   ds_read_b128 at a half-uniform address (same-address broadcast is free;
//   the two halves are 2-way which is also free) instead of 3 ds_bpermute +
//   clamp/selects per slot: per-pass overhead drops ~50 ops -> ~10.
//   Same wave produces and consumes -> no barrier; compiler orders the
//   aliasing ds ops via lgkmcnt. projT loads / fdot2 schedule unchanged.
// ---------------------------------------------------------------------------
__global__ __launch_bounds__(256) void gather_kernel(
    const int* __restrict__ deg, const int* __restrict__ offs,
    const ushort* __restrict__ csr,
    const float* __restrict__ s_src, const float* __restrict__ s_tgt,
    const ushort* __restrict__ projT, float* __restrict__ out)
{
    __shared__ uint4 edata[4][MAXDEG];     // 4 waves x 64 slots x 16 B = 4 KB

    const int wv   = threadIdx.x >> 6;
    const int lane = threadIdx.x & 63;
    const int node = blockIdx.x * 4 + wv;  // N_NODES = 12500*4

    int n = deg[node];
    n = (n < MAXDEG) ? n : MAXDEG;
    const int o = offs[node];

    uint4 ed = make_uint4(0u, 0u, 0u, 0u);
    if (lane < n) {
        int tgt = csr[o + lane];                            // coalesced ushort
        float4 ss = *(const float4*)&s_src[node * N_HEADS]; // wave-uniform
        float4 st = *(const float4*)&s_tgt[tgt * N_HEADS];  // parallel gather

        float sc[4] = { ss.x + st.x, ss.y + st.y, ss.z + st.z, ss.w + st.w };
        float mx = -1e30f;
#pragma unroll
        for (int h = 0; h < 4; ++h) {
            sc[h] = (sc[h] > 0.0f) ? sc[h] : 0.01f * sc[h];  // leaky_relu
            mx = fmaxf(mx, sc[h]);
        }
        float sum = 0.0f;
#pragma unroll
        for (int h = 0; h < 4; ++h) {
            sc[h] = __expf(sc[h] - mx);
            sum += sc[h];
        }
        float inv = 0.25f / sum;     // softmax normalize * head-mean

        h2 a01, a23;
        a01.x = (_Float16)(sc[0] * inv);
        a01.y = (_Float16)(sc[1] * inv);
        a23.x = (_Float16)(sc[2] * inv);
        a23.y = (_Float16)(sc[3] * inv);
        ed.x = (unsigned)tgt;
        ed.y = __builtin_bit_cast(unsigned, a01);
        ed.z = __builtin_bit_cast(unsigned, a23);
    }
    edata[wv][lane] = ed;            // all 64 lanes write (dead slots zeroed)
    // no barrier: same wave produces and consumes (lgkmcnt ordering)

    const int d    = lane & 31;
    const int half = lane >> 5;

    float acc0 = 0.0f, acc1 = 0.0f, acc2 = 0.0f, acc3 = 0.0f;

    // 16 edge slots per iteration (8 per half), 8 outstanding projT gathers
    // per lane; slot metadata via broadcast ds_read_b128.
    for (int j = 0; j < n; j += 16) {
        uint4 s[8];
#pragma unroll
        for (int u = 0; u < 8; ++u)
            s[u] = edata[wv][j + 2 * u + half];   // half-uniform broadcast
        uint2 p[8];
#pragma unroll
        for (int u = 0; u < 8; ++u)
            p[u] = *(const uint2*)&projT[(long long)s[u].x * PROJ_DIM + d * 4];
#pragma unroll
        for (int u = 0; u < 8; ++u) {
            h2 a  = __builtin_bit_cast(h2, s[u].y);
            h2 b  = __builtin_bit_cast(h2, s[u].z);
            h2 lo = __builtin_bit_cast(h2, p[u].x);
            h2 hi = __builtin_bit_cast(h2, p[u].y);
            float* accp = (u & 1) ? ((u & 2) ? &acc3 : &acc1)
                                  : ((u & 2) ? &acc2 : &acc0);
            float tt = *accp;
#if __has_builtin(__builtin_amdgcn_fdot2)
            tt = __builtin_amdgcn_fdot2(a, lo, tt, false);   // v_dot2_f32_f16
            tt = __builtin_amdgcn_fdot2(b, hi, tt, false);
#else
            tt = fmaf((float)a.x, (float)lo.x, tt);          // v_fma_mix_f32
            tt = fmaf((float)a.y, (float)lo.y, tt);
            tt = fmaf((float)b.x, (float)hi.x, tt);
            tt = fmaf((float)b.y, (float)hi.y, tt);
#endif
            *accp = tt;
        }
    }

    float acc = (acc0 + acc1) + (acc2 + acc3);
    acc += __shfl_down(acc, 32);      // combine the two halves (width 64)
    if (lane < 32) out[node * OUT_DIM + d] = acc;
}

extern "C" void kernel_launch(void* const* d_in, const int* in_sizes, int n_in,
                              void* d_out, int out_size, void* d_ws, size_t ws_size,
                              hipStream_t stream) {
    const float* X   = (const float*)d_in[0];
    const int*   ei  = (const int*)d_in[1];
    const float* W   = (const float*)d_in[2];
    const float* att = (const float*)d_in[3];
    float* out = (float*)d_out;

    // workspace layout, total ~20.8 MB
    char* p = (char*)d_ws;
    ushort* projT   = (ushort*)p;   p += (size_t)N_NODES * PROJ_DIM * 2;  // 12.8 MB
    float* s_src    = (float*)p;    p += (size_t)N_NODES * N_HEADS * 4;   // 0.8 MB
    float* s_tgt    = (float*)p;    p += (size_t)N_NODES * N_HEADS * 4;   // 0.8 MB
    unsigned* slab  = (unsigned*)p; p += (size_t)NBIN * BINCAP * 4;       // 3.92 MB
    ushort* csr     = (ushort*)p;   p += (size_t)NBIN * BINCAP * 2;       // 1.96 MB
    int* offs       = (int*)p;      p += (size_t)N_NODES * 4;             // 0.2 MB
    int* deg        = (int*)p;      p += (size_t)N_NODES * 4;             // 0.2 MB
    int* bin_cursor = (int*)p;      p += 256 * 4;

    (void)hipMemsetAsync(bin_cursor, 0, 256 * sizeof(int), stream);

    partition_kernel<<<PART_BLKS, 256, 0, stream>>>(ei, bin_cursor, slab);

    fused_kernel<<<FUSE_BLKS, 256, 0, stream>>>(
        X, W, att, slab, bin_cursor, projT, s_src, s_tgt, csr, offs, deg);

    gather_kernel<<<N_NODES / 4, 256, 0, stream>>>(
        deg, offs, csr, s_src, s_tgt, projT, out);
}